// Round 2
// baseline (926.804 us; speedup 1.0000x reference)
//
#include <hip/hip_runtime.h>
#include <cstddef>
#include <cstdint>

typedef unsigned short u16;
typedef unsigned int   u32;

#define DEV __device__ __forceinline__

DEV float b2f(u16 u) { union { u32 i; float f; } c; c.i = ((u32)u) << 16; return c.f; }
DEV u16 f2b(float x) { union { float f; u32 i; } c; c.f = x; u32 b = c.i;
                       return (u16)((b + 0x7FFFu + ((b >> 16) & 1u)) >> 16); }
DEV float sigm(float x)  { return 1.0f / (1.0f + __expf(-x)); }
DEV float tanh_(float x) { return 1.0f - 2.0f / (1.0f + __expf(2.0f * x)); }
DEV float gelu_(float x) { return 0.5f * x * (1.0f + erff(x * 0.70710678118654752f)); }

// ---- workspace byte offsets (all 256B-aligned; total 144,113,664 B = 137.4 MiB) ----
#define OB_P    0ull            // [40000][768] bf16 : Pr | Pz_x | Ph_x
#define OB_H    61440000ull     // [40000][256] bf16
#define OB_UH   81920000ull     // [40000][256] bf16
#define OB_SH   102400000ull    // [40000][256] bf16
#define OB_SGH  122880000ull    // [40000][256] bf16 (reused as nei f32 [20000][256] after loop)
#define OB_BPRE 143360000ull    // [112][768] bf16 (K-padded, row111=0)
#define OB_BZ   143532032ull    // [256][256] bf16
#define OB_BH   143663104ull
#define OB_BU   143794176ull
#define OB_BOH  143925248ull
#define OB_BON  144056320ull    // [112][256] bf16 (K-padded, rows 98..111 = 0)
#define WS_BYTES 144113664ull

// ---------------------------------------------------------------------------
// Repack weights into [K][N] n-contiguous bf16 operands (K padded to mult 16).
__global__ __launch_bounds__(256) void k_repack(
    const float* __restrict__ Wz, const float* __restrict__ Wr,
    const float* __restrict__ Ur, const float* __restrict__ Wh,
    const float* __restrict__ Wo,
    u16* __restrict__ Bpre, u16* __restrict__ Bz, u16* __restrict__ Bh,
    u16* __restrict__ Bu, u16* __restrict__ Boh, u16* __restrict__ Bon) {
    int idx = blockIdx.x * 256 + threadIdx.x;     // grid covers 86,016
    if (idx < 112 * 768) {
        int k = idx / 768, j = idx % 768;
        float v = 0.0f;
        if (k < 111) {
            if (j < 256)       v = Wr[j * 111 + k];
            else if (j < 512)  v = Wz[(j - 256) * 367 + k];
            else               v = Wh[(j - 512) * 367 + k];
        }
        Bpre[idx] = f2b(v);
    }
    if (idx < 65536) {
        int k = idx >> 8, n = idx & 255;
        Bz[idx]  = f2b(Wz[n * 367 + 111 + k]);
        Bh[idx]  = f2b(Wh[n * 367 + 111 + k]);
        Bu[idx]  = f2b(Ur[n * 256 + k]);
        Boh[idx] = f2b(Wo[n * 354 + 98 + k]);
    }
    if (idx < 112 * 256) {
        int k = idx >> 8, n = idx & 255;
        Bon[idx] = f2b(k < 98 ? Wo[n * 354 + k] : 0.0f);
    }
}

// ---------------------------------------------------------------------------
// P = gathered_x @ Bpre.  M=40000(625 tiles) N=768(12) K=112. A gathered on the fly.
__global__ __launch_bounds__(256) void k_gemm_p(
    const float* __restrict__ fnode, const float* __restrict__ fmess,
    const u16* __restrict__ Bpre, u16* __restrict__ P) {
    int bm = blockIdx.x / 12, bn = blockIdx.x % 12;
    int m0 = bm << 6, n0 = bn << 6;
    __shared__ float As[16][64], Bs[16][64];
    int tid = threadIdx.x;
    int tx = tid & 15, ty = tid >> 4;
    int ar = tid >> 2, ac = (tid & 3) << 2;
    int br = tid >> 4, bc = (tid & 15) << 2;
    int e = m0 + ar;
    int src = (int)fmess[(size_t)e * 15];
    const float* fn = fnode + (size_t)src * 98;
    const float* fm = fmess + (size_t)e * 15 + 2;
    float acc[4][4] = {};
    for (int k0 = 0; k0 < 112; k0 += 16) {
        #pragma unroll
        for (int i = 0; i < 4; ++i) {
            int k = k0 + ac + i;
            float v = 0.0f;
            if (k < 98) v = fn[k];
            else if (k < 111) v = fm[k - 98];
            As[ac + i][ar] = v;
        }
        ushort4 bv = *(const ushort4*)(Bpre + (size_t)(k0 + br) * 768 + n0 + bc);
        Bs[br][bc + 0] = b2f(bv.x); Bs[br][bc + 1] = b2f(bv.y);
        Bs[br][bc + 2] = b2f(bv.z); Bs[br][bc + 3] = b2f(bv.w);
        __syncthreads();
        #pragma unroll
        for (int k = 0; k < 16; ++k) {
            float a[4], b[4];
            *(float4*)a = *(const float4*)&As[k][ty << 2];
            *(float4*)b = *(const float4*)&Bs[k][tx << 2];
            #pragma unroll
            for (int i = 0; i < 4; ++i)
                #pragma unroll
                for (int j = 0; j < 4; ++j)
                    acc[i][j] = fmaf(a[i], b[j], acc[i][j]);
        }
        __syncthreads();
    }
    #pragma unroll
    for (int i = 0; i < 4; ++i) {
        int m = m0 + (ty << 2) + i;
        ushort4 o;
        o.x = f2b(acc[i][0]); o.y = f2b(acc[i][1]);
        o.z = f2b(acc[i][2]); o.w = f2b(acc[i][3]);
        *(ushort4*)(P + (size_t)m * 768 + n0 + (tx << 2)) = o;
    }
}

// ---------------------------------------------------------------------------
// Uh = h @ Bu.  bf16 A/B/C.  M=40000(625) N=256(4) K=256.
__global__ __launch_bounds__(256) void k_gemm_uh(
    const u16* __restrict__ A, const u16* __restrict__ B, u16* __restrict__ C) {
    int bm = blockIdx.x >> 2, bn = blockIdx.x & 3;
    int m0 = bm << 6, n0 = bn << 6;
    __shared__ float As[16][64], Bs[16][64];
    int tid = threadIdx.x;
    int tx = tid & 15, ty = tid >> 4;
    int ar = tid >> 2, ac = (tid & 3) << 2;
    int br = tid >> 4, bc = (tid & 15) << 2;
    float acc[4][4] = {};
    for (int k0 = 0; k0 < 256; k0 += 16) {
        ushort4 av = *(const ushort4*)(A + (size_t)(m0 + ar) * 256 + k0 + ac);
        As[ac + 0][ar] = b2f(av.x); As[ac + 1][ar] = b2f(av.y);
        As[ac + 2][ar] = b2f(av.z); As[ac + 3][ar] = b2f(av.w);
        ushort4 bv = *(const ushort4*)(B + (size_t)(k0 + br) * 256 + n0 + bc);
        Bs[br][bc + 0] = b2f(bv.x); Bs[br][bc + 1] = b2f(bv.y);
        Bs[br][bc + 2] = b2f(bv.z); Bs[br][bc + 3] = b2f(bv.w);
        __syncthreads();
        #pragma unroll
        for (int k = 0; k < 16; ++k) {
            float a[4], b[4];
            *(float4*)a = *(const float4*)&As[k][ty << 2];
            *(float4*)b = *(const float4*)&Bs[k][tx << 2];
            #pragma unroll
            for (int i = 0; i < 4; ++i)
                #pragma unroll
                for (int j = 0; j < 4; ++j)
                    acc[i][j] = fmaf(a[i], b[j], acc[i][j]);
        }
        __syncthreads();
    }
    #pragma unroll
    for (int i = 0; i < 4; ++i) {
        int m = m0 + (ty << 2) + i;
        ushort4 o;
        o.x = f2b(acc[i][0]); o.y = f2b(acc[i][1]);
        o.z = f2b(acc[i][2]); o.w = f2b(acc[i][3]);
        *(ushort4*)(C + (size_t)m * 256 + n0 + (tx << 2)) = o;
    }
}

// ---------------------------------------------------------------------------
// Pn = fnode @ Bon  -> d_out (f32).  M=20000(313) N=256(4) K=112.
__global__ __launch_bounds__(256) void k_gemm_pn(
    const float* __restrict__ fnode, const u16* __restrict__ Bon,
    float* __restrict__ Pn) {
    int bm = blockIdx.x >> 2, bn = blockIdx.x & 3;
    int m0 = bm << 6, n0 = bn << 6;
    __shared__ float As[16][64], Bs[16][64];
    int tid = threadIdx.x;
    int tx = tid & 15, ty = tid >> 4;
    int ar = tid >> 2, ac = (tid & 3) << 2;
    int br = tid >> 4, bc = (tid & 15) << 2;
    int am = m0 + ar;
    float acc[4][4] = {};
    for (int k0 = 0; k0 < 112; k0 += 16) {
        #pragma unroll
        for (int i = 0; i < 4; ++i) {
            int k = k0 + ac + i;
            As[ac + i][ar] = (am < 20000 && k < 98) ? fnode[(size_t)am * 98 + k] : 0.0f;
        }
        ushort4 bv = *(const ushort4*)(Bon + (size_t)(k0 + br) * 256 + n0 + bc);
        Bs[br][bc + 0] = b2f(bv.x); Bs[br][bc + 1] = b2f(bv.y);
        Bs[br][bc + 2] = b2f(bv.z); Bs[br][bc + 3] = b2f(bv.w);
        __syncthreads();
        #pragma unroll
        for (int k = 0; k < 16; ++k) {
            float a[4], b[4];
            *(float4*)a = *(const float4*)&As[k][ty << 2];
            *(float4*)b = *(const float4*)&Bs[k][tx << 2];
            #pragma unroll
            for (int i = 0; i < 4; ++i)
                #pragma unroll
                for (int j = 0; j < 4; ++j)
                    acc[i][j] = fmaf(a[i], b[j], acc[i][j]);
        }
        __syncthreads();
    }
    #pragma unroll
    for (int i = 0; i < 4; ++i) {
        int m = m0 + (ty << 2) + i;
        if (m < 20000)
            *(float4*)(Pn + (size_t)m * 256 + n0 + (tx << 2)) =
                make_float4(acc[i][0], acc[i][1], acc[i][2], acc[i][3]);
    }
}

// ---------------------------------------------------------------------------
// Depth 1 (h==0): h = sigm(Pz+bz) * tanh(Ph+bh), row 0 masked.
__global__ __launch_bounds__(256) void k_depth1(
    const u16* __restrict__ P, const float* __restrict__ bz,
    const float* __restrict__ bh, u16* __restrict__ h) {
    int idx = blockIdx.x * 256 + threadIdx.x;   // 40000*64 slots
    int e = idx >> 6, c = (idx & 63) << 2;
    ushort4 pz4 = *(const ushort4*)(P + (size_t)e * 768 + 256 + c);
    ushort4 ph4 = *(const ushort4*)(P + (size_t)e * 768 + 512 + c);
    float4 vz = *(const float4*)(bz + c);
    float4 vh = *(const float4*)(bh + c);
    float r0 = sigm(b2f(pz4.x) + vz.x) * tanh_(b2f(ph4.x) + vh.x);
    float r1 = sigm(b2f(pz4.y) + vz.y) * tanh_(b2f(ph4.y) + vh.y);
    float r2 = sigm(b2f(pz4.z) + vz.z) * tanh_(b2f(ph4.z) + vh.z);
    float r3 = sigm(b2f(pz4.w) + vz.w) * tanh_(b2f(ph4.w) + vh.w);
    if (e == 0) { r0 = r1 = r2 = r3 = 0.0f; }
    ushort4 o; o.x = f2b(r0); o.y = f2b(r1); o.z = f2b(r2); o.w = f2b(r3);
    *(ushort4*)(h + (size_t)e * 256 + c) = o;
}

// ---------------------------------------------------------------------------
// Per-edge gather: sumh = sum_j h[bg];  sumgh = sum_j sigm(Pr+Uh[bg]+urb)*h[bg]
__global__ __launch_bounds__(256) void k_gather_edge(
    const u16* __restrict__ h, const u16* __restrict__ Uh,
    const u16* __restrict__ P, const float* __restrict__ urb,
    const int* __restrict__ bgraph,
    u16* __restrict__ sumh, u16* __restrict__ sumgh) {
    int e = (blockIdx.x << 2) + (threadIdx.x >> 6);
    int c = (threadIdx.x & 63) << 2;
    ushort4 pr4 = *(const ushort4*)(P + (size_t)e * 768 + c);
    float4 ub = *(const float4*)(urb + c);
    float pr[4] = {b2f(pr4.x) + ub.x, b2f(pr4.y) + ub.y,
                   b2f(pr4.z) + ub.z, b2f(pr4.w) + ub.w};
    float sh[4] = {}, sg[4] = {};
    #pragma unroll
    for (int j = 0; j < 6; ++j) {
        int b = bgraph[e * 6 + j];
        ushort4 hv4 = *(const ushort4*)(h + (size_t)b * 256 + c);
        ushort4 uv4 = *(const ushort4*)(Uh + (size_t)b * 256 + c);
        float hv[4] = {b2f(hv4.x), b2f(hv4.y), b2f(hv4.z), b2f(hv4.w)};
        float uv[4] = {b2f(uv4.x), b2f(uv4.y), b2f(uv4.z), b2f(uv4.w)};
        #pragma unroll
        for (int q = 0; q < 4; ++q) {
            sh[q] += hv[q];
            sg[q] += sigm(pr[q] + uv[q]) * hv[q];
        }
    }
    ushort4 o1, o2;
    o1.x = f2b(sh[0]); o1.y = f2b(sh[1]); o1.z = f2b(sh[2]); o1.w = f2b(sh[3]);
    o2.x = f2b(sg[0]); o2.y = f2b(sg[1]); o2.z = f2b(sg[2]); o2.w = f2b(sg[3]);
    *(ushort4*)(sumh  + (size_t)e * 256 + c) = o1;
    *(ushort4*)(sumgh + (size_t)e * 256 + c) = o2;
}

// ---------------------------------------------------------------------------
// Fused dual GEMM + GRU: z = sigm(sumh@Bz+Pz+bz); pre = tanh(sumgh@Bh+Ph+bh);
// h = ((1-z)*sumh + z*pre) * emask.  M=40000(625) N=256(4) K=256.
__global__ __launch_bounds__(256) void k_depth_fused(
    const u16* __restrict__ sumh, const u16* __restrict__ sumgh,
    const u16* __restrict__ Bz, const u16* __restrict__ Bh,
    const u16* __restrict__ P, const float* __restrict__ bz,
    const float* __restrict__ bh, u16* __restrict__ h) {
    int bm = blockIdx.x >> 2, bn = blockIdx.x & 3;
    int m0 = bm << 6, n0 = bn << 6;
    __shared__ float As1[16][64], As2[16][64], Bs1[16][64], Bs2[16][64];
    int tid = threadIdx.x;
    int tx = tid & 15, ty = tid >> 4;
    int ar = tid >> 2, ac = (tid & 3) << 2;
    int br = tid >> 4, bc = (tid & 15) << 2;
    float accZ[4][4] = {}, accH[4][4] = {};
    for (int k0 = 0; k0 < 256; k0 += 16) {
        ushort4 a1 = *(const ushort4*)(sumh  + (size_t)(m0 + ar) * 256 + k0 + ac);
        ushort4 a2 = *(const ushort4*)(sumgh + (size_t)(m0 + ar) * 256 + k0 + ac);
        As1[ac + 0][ar] = b2f(a1.x); As1[ac + 1][ar] = b2f(a1.y);
        As1[ac + 2][ar] = b2f(a1.z); As1[ac + 3][ar] = b2f(a1.w);
        As2[ac + 0][ar] = b2f(a2.x); As2[ac + 1][ar] = b2f(a2.y);
        As2[ac + 2][ar] = b2f(a2.z); As2[ac + 3][ar] = b2f(a2.w);
        ushort4 b1 = *(const ushort4*)(Bz + (size_t)(k0 + br) * 256 + n0 + bc);
        ushort4 b2 = *(const ushort4*)(Bh + (size_t)(k0 + br) * 256 + n0 + bc);
        Bs1[br][bc + 0] = b2f(b1.x); Bs1[br][bc + 1] = b2f(b1.y);
        Bs1[br][bc + 2] = b2f(b1.z); Bs1[br][bc + 3] = b2f(b1.w);
        Bs2[br][bc + 0] = b2f(b2.x); Bs2[br][bc + 1] = b2f(b2.y);
        Bs2[br][bc + 2] = b2f(b2.z); Bs2[br][bc + 3] = b2f(b2.w);
        __syncthreads();
        #pragma unroll
        for (int k = 0; k < 16; ++k) {
            float a1v[4], a2v[4], b1v[4], b2v[4];
            *(float4*)a1v = *(const float4*)&As1[k][ty << 2];
            *(float4*)a2v = *(const float4*)&As2[k][ty << 2];
            *(float4*)b1v = *(const float4*)&Bs1[k][tx << 2];
            *(float4*)b2v = *(const float4*)&Bs2[k][tx << 2];
            #pragma unroll
            for (int i = 0; i < 4; ++i)
                #pragma unroll
                for (int j = 0; j < 4; ++j) {
                    accZ[i][j] = fmaf(a1v[i], b1v[j], accZ[i][j]);
                    accH[i][j] = fmaf(a2v[i], b2v[j], accH[i][j]);
                }
        }
        __syncthreads();
    }
    int nb = n0 + (tx << 2);
    float4 bz4 = *(const float4*)(bz + nb);
    float4 bh4 = *(const float4*)(bh + nb);
    const float bzv[4] = {bz4.x, bz4.y, bz4.z, bz4.w};
    const float bhv[4] = {bh4.x, bh4.y, bh4.z, bh4.w};
    #pragma unroll
    for (int i = 0; i < 4; ++i) {
        int m = m0 + (ty << 2) + i;
        ushort4 pz4 = *(const ushort4*)(P + (size_t)m * 768 + 256 + nb);
        ushort4 ph4 = *(const ushort4*)(P + (size_t)m * 768 + 512 + nb);
        ushort4 sh4 = *(const ushort4*)(sumh + (size_t)m * 256 + nb);
        float pzv[4] = {b2f(pz4.x), b2f(pz4.y), b2f(pz4.z), b2f(pz4.w)};
        float phv[4] = {b2f(ph4.x), b2f(ph4.y), b2f(ph4.z), b2f(ph4.w)};
        float shv[4] = {b2f(sh4.x), b2f(sh4.y), b2f(sh4.z), b2f(sh4.w)};
        float o[4];
        #pragma unroll
        for (int j = 0; j < 4; ++j) {
            float z   = sigm(accZ[i][j] + pzv[j] + bzv[j]);
            float pre = tanh_(accH[i][j] + phv[j] + bhv[j]);
            o[j] = (1.0f - z) * shv[j] + z * pre;
        }
        if (m == 0) { o[0] = o[1] = o[2] = o[3] = 0.0f; }
        ushort4 ov;
        ov.x = f2b(o[0]); ov.y = f2b(o[1]); ov.z = f2b(o[2]); ov.w = f2b(o[3]);
        *(ushort4*)(h + (size_t)m * 256 + nb) = ov;
    }
}

// ---------------------------------------------------------------------------
// nei[n] = sum_j h[agraph[n][j]]  (f32 out, into freed sumgh region)
__global__ __launch_bounds__(256) void k_gather_node(
    const u16* __restrict__ h, const int* __restrict__ agraph,
    float* __restrict__ nei) {
    int n = (blockIdx.x << 2) + (threadIdx.x >> 6);
    int c = (threadIdx.x & 63) << 2;
    float s[4] = {};
    #pragma unroll
    for (int j = 0; j < 6; ++j) {
        int a = agraph[n * 6 + j];
        ushort4 hv = *(const ushort4*)(h + (size_t)a * 256 + c);
        s[0] += b2f(hv.x); s[1] += b2f(hv.y); s[2] += b2f(hv.z); s[3] += b2f(hv.w);
    }
    *(float4*)(nei + (size_t)n * 256 + c) = make_float4(s[0], s[1], s[2], s[3]);
}

// ---------------------------------------------------------------------------
// out = gelu(nei@Boh + Pn + bo), row 0 masked.  Pn lives in d_out; in-place safe.
// M=20000(313) N=256(4) K=256.
__global__ __launch_bounds__(256) void k_readout(
    const float* __restrict__ nei, const u16* __restrict__ Boh,
    const float* __restrict__ bo, float* __restrict__ out) {
    int bm = blockIdx.x >> 2, bn = blockIdx.x & 3;
    int m0 = bm << 6, n0 = bn << 6;
    __shared__ float As[16][64], Bs[16][64];
    int tid = threadIdx.x;
    int tx = tid & 15, ty = tid >> 4;
    int ar = tid >> 2, ac = (tid & 3) << 2;
    int br = tid >> 4, bc = (tid & 15) << 2;
    int am = m0 + ar;
    float acc[4][4] = {};
    for (int k0 = 0; k0 < 256; k0 += 16) {
        float4 av = (am < 20000) ? *(const float4*)(nei + (size_t)am * 256 + k0 + ac)
                                 : make_float4(0.f, 0.f, 0.f, 0.f);
        As[ac + 0][ar] = av.x; As[ac + 1][ar] = av.y;
        As[ac + 2][ar] = av.z; As[ac + 3][ar] = av.w;
        ushort4 bv = *(const ushort4*)(Boh + (size_t)(k0 + br) * 256 + n0 + bc);
        Bs[br][bc + 0] = b2f(bv.x); Bs[br][bc + 1] = b2f(bv.y);
        Bs[br][bc + 2] = b2f(bv.z); Bs[br][bc + 3] = b2f(bv.w);
        __syncthreads();
        #pragma unroll
        for (int k = 0; k < 16; ++k) {
            float a[4], b[4];
            *(float4*)a = *(const float4*)&As[k][ty << 2];
            *(float4*)b = *(const float4*)&Bs[k][tx << 2];
            #pragma unroll
            for (int i = 0; i < 4; ++i)
                #pragma unroll
                for (int j = 0; j < 4; ++j)
                    acc[i][j] = fmaf(a[i], b[j], acc[i][j]);
        }
        __syncthreads();
    }
    int nb = n0 + (tx << 2);
    float4 bo4 = *(const float4*)(bo + nb);
    const float bov[4] = {bo4.x, bo4.y, bo4.z, bo4.w};
    #pragma unroll
    for (int i = 0; i < 4; ++i) {
        int m = m0 + (ty << 2) + i;
        if (m >= 20000) continue;
        float4 pn = *(const float4*)(out + (size_t)m * 256 + nb);
        const float pnv[4] = {pn.x, pn.y, pn.z, pn.w};
        float o[4];
        #pragma unroll
        for (int j = 0; j < 4; ++j)
            o[j] = gelu_(acc[i][j] + pnv[j] + bov[j]);
        if (m == 0) { o[0] = o[1] = o[2] = o[3] = 0.0f; }
        *(float4*)(out + (size_t)m * 256 + nb) = make_float4(o[0], o[1], o[2], o[3]);
    }
}

// ---------------------------------------------------------------------------
extern "C" void kernel_launch(void* const* d_in, const int* in_sizes, int n_in,
                              void* d_out, int out_size, void* d_ws, size_t ws_size,
                              hipStream_t stream) {
    if (ws_size < WS_BYTES) return;   // need 137.4 MiB scratch

    const float* fnode  = (const float*)d_in[0];
    const float* fmess  = (const float*)d_in[1];
    const int*   agraph = (const int*)d_in[2];
    const int*   bgraph = (const int*)d_in[3];
    const float* Wz  = (const float*)d_in[4];
    const float* bz  = (const float*)d_in[5];
    const float* Wr  = (const float*)d_in[6];
    const float* Ur  = (const float*)d_in[7];
    const float* urb = (const float*)d_in[8];
    const float* Wh  = (const float*)d_in[9];
    const float* bh  = (const float*)d_in[10];
    const float* Wo  = (const float*)d_in[11];
    const float* bo  = (const float*)d_in[12];

    char* base = (char*)d_ws;
    u16* P    = (u16*)(base + OB_P);
    u16* h    = (u16*)(base + OB_H);
    u16* Uh   = (u16*)(base + OB_UH);
    u16* sh   = (u16*)(base + OB_SH);
    u16* sgh  = (u16*)(base + OB_SGH);
    u16* Bpre = (u16*)(base + OB_BPRE);
    u16* Bz   = (u16*)(base + OB_BZ);
    u16* Bh   = (u16*)(base + OB_BH);
    u16* Bu   = (u16*)(base + OB_BU);
    u16* Boh  = (u16*)(base + OB_BOH);
    u16* Bon  = (u16*)(base + OB_BON);
    float* nei = (float*)(base + OB_SGH);   // reuse after loop
    float* out = (float*)d_out;             // Pn lives here, then final output

    hipLaunchKernelGGL(k_repack, dim3(336), dim3(256), 0, stream,
                       Wz, Wr, Ur, Wh, Wo, Bpre, Bz, Bh, Bu, Boh, Bon);
    hipLaunchKernelGGL(k_gemm_p, dim3(625 * 12), dim3(256), 0, stream,
                       fnode, fmess, Bpre, P);
    hipLaunchKernelGGL(k_gemm_pn, dim3(313 * 4), dim3(256), 0, stream,
                       fnode, Bon, out);
    hipLaunchKernelGGL(k_depth1, dim3(10000), dim3(256), 0, stream, P, bz, bh, h);
    for (int d = 1; d < 4; ++d) {
        hipLaunchKernelGGL(k_gemm_uh, dim3(625 * 4), dim3(256), 0, stream, h, Bu, Uh);
        hipLaunchKernelGGL(k_gather_edge, dim3(10000), dim3(256), 0, stream,
                           h, Uh, P, urb, bgraph, sh, sgh);
        hipLaunchKernelGGL(k_depth_fused, dim3(2500), dim3(256), 0, stream,
                           sh, sgh, Bz, Bh, P, bz, bh, h);
    }
    hipLaunchKernelGGL(k_gather_node, dim3(5000), dim3(256), 0, stream, h, agraph, nei);
    hipLaunchKernelGGL(k_readout, dim3(313 * 4), dim3(256), 0, stream, nei, Boh, bo, out);
}

// Round 3
// 483.475 us; speedup vs baseline: 1.9170x; 1.9170x over previous
//
#include <hip/hip_runtime.h>
#include <cstddef>
#include <cstdint>

typedef unsigned short u16;
typedef unsigned int   u32;
typedef __bf16  bf16x8 __attribute__((ext_vector_type(8)));
typedef float   f32x4  __attribute__((ext_vector_type(4)));

#define DEV __device__ __forceinline__

DEV float b2f(u16 u) { union { u32 i; float f; } c; c.i = ((u32)u) << 16; return c.f; }
DEV u16 f2b(float x) { union { float f; u32 i; } c; c.f = x; u32 b = c.i;
                       return (u16)((b + 0x7FFFu + ((b >> 16) & 1u)) >> 16); }
DEV float sigm(float x)  { return 1.0f / (1.0f + __expf(-x)); }
DEV float tanh_(float x) { return 1.0f - 2.0f / (1.0f + __expf(2.0f * x)); }
DEV float gelu_(float x) { return 0.5f * x * (1.0f + erff(x * 0.70710678118654752f)); }

DEV void u4tof8(uint4 v, float* f) {
    f[0] = b2f((u16)(v.x & 0xFFFF)); f[1] = b2f((u16)(v.x >> 16));
    f[2] = b2f((u16)(v.y & 0xFFFF)); f[3] = b2f((u16)(v.y >> 16));
    f[4] = b2f((u16)(v.z & 0xFFFF)); f[5] = b2f((u16)(v.z >> 16));
    f[6] = b2f((u16)(v.w & 0xFFFF)); f[7] = b2f((u16)(v.w >> 16));
}
DEV uint4 f8tou4(const float* f) {
    uint4 v;
    v.x = (u32)f2b(f[0]) | ((u32)f2b(f[1]) << 16);
    v.y = (u32)f2b(f[2]) | ((u32)f2b(f[3]) << 16);
    v.z = (u32)f2b(f[4]) | ((u32)f2b(f[5]) << 16);
    v.w = (u32)f2b(f[6]) | ((u32)f2b(f[7]) << 16);
    return v;
}

// ---- workspace byte offsets; total 143,949,824 B (<= 144,113,664 proven to fit) ----
#define OB_H     0ull           // h     [40000][256] bf16 (A: overrun spills into SH)
#define OB_SH    20480000ull    // sumh  [40000][256] bf16 ; x [40000][128] overlays early
#define OB_SGH   40960000ull    // sumgh [40000][256] bf16 ; fnode_b [20000][128] overlays early
#define OB_UH    61440000ull    // Uh    [40000][256] bf16 ; nei_b [20000][256] overlays late
#define OB_BPRE  77440000ull    // BpreT [768][128] bf16 (inside UH region; dead before Uh written)
#define OB_BZ    81920000ull    // [256][256] bf16  W_z_w[:,111:]
#define OB_BH    82051072ull    // [256][256] bf16  W_h_w[:,111:]
#define OB_BU    82182144ull    // [256][256] bf16  U_r_w
#define OB_BOH   82313216ull    // [256][256] bf16  W_o_w[:,98:]
#define OB_BON   82444288ull    // [256][128] bf16  W_o_w[:,:98] (K-padded)
#define OB_PR    82509824ull    // Pr [40000][256] bf16
#define OB_PZ    102989824ull   // Pz [40000][256] bf16
#define OB_PH    123469824ull   // Ph [40000][256] bf16 (element-read only; last region)
#define WS_BYTES 143949824ull

// ---------------------------------------------------------------------------
// Weight repack -> [N][K] bf16 (K padded where needed). Grid 384x256.
__global__ __launch_bounds__(256) void k_repack(
    const float* __restrict__ Wz, const float* __restrict__ Wr,
    const float* __restrict__ Ur, const float* __restrict__ Wh,
    const float* __restrict__ Wo,
    u16* __restrict__ BpreT, u16* __restrict__ BzT, u16* __restrict__ BhT,
    u16* __restrict__ BuT, u16* __restrict__ BohT, u16* __restrict__ BonT) {
    int idx = blockIdx.x * 256 + threadIdx.x;
    if (idx < 98304) {                 // BpreT [768][128]: Wr | Wz_x | Wh_x
        int n = idx >> 7, k = idx & 127;
        float v = 0.0f;
        if (k < 111) {
            if (n < 256)       v = Wr[n * 111 + k];
            else if (n < 512)  v = Wz[(n - 256) * 367 + k];
            else               v = Wh[(n - 512) * 367 + k];
        }
        BpreT[idx] = f2b(v);
    }
    if (idx < 65536) {                 // [256][256] slices
        int n = idx >> 8, k = idx & 255;
        BzT[idx]  = f2b(Wz[n * 367 + 111 + k]);
        BhT[idx]  = f2b(Wh[n * 367 + 111 + k]);
        BuT[idx]  = f2b(Ur[n * 256 + k]);
        BohT[idx] = f2b(Wo[n * 354 + 98 + k]);
    }
    if (idx < 32768) {                 // BonT [256][128]
        int n = idx >> 7, k = idx & 127;
        BonT[idx] = f2b(k < 98 ? Wo[n * 354 + k] : 0.0f);
    }
}

// x[e][c] (bf16, [40000][128], zero K-pad). Grid 40000x128.
__global__ void k_build_x(const float* __restrict__ fnode,
                          const float* __restrict__ fmess, u16* __restrict__ x) {
    int e = blockIdx.x, c = threadIdx.x;
    int src = (int)fmess[(size_t)e * 15];
    float v = 0.0f;
    if (c < 98)       v = fnode[(size_t)src * 98 + c];
    else if (c < 111) v = fmess[(size_t)e * 15 + 2 + (c - 98)];
    x[(size_t)e * 128 + c] = f2b(v);
}

// fnode_b [20000][128] bf16 zero-padded. Grid 10000x256.
__global__ __launch_bounds__(256) void k_build_fb(const float* __restrict__ fnode,
                                                  u16* __restrict__ fb) {
    int idx = blockIdx.x * 256 + threadIdx.x;
    int n = idx >> 7, c = idx & 127;
    fb[idx] = f2b(c < 98 ? fnode[(size_t)n * 98 + c] : 0.0f);
}

// ---------------------------------------------------------------------------
// MFMA tile helpers: 128x64 bf16 tiles, XOR-swizzled LDS (byte ^= (row&7)<<4).
DEV void stage128x64(const u16* __restrict__ g, size_t row0, int ld, int k0,
                     u16* s, int tid) {
    #pragma unroll
    for (int it = 0; it < 4; ++it) {
        int r = it * 32 + (tid >> 3);
        int c = (tid & 7) << 3;
        uint4 v = *(const uint4*)(g + (row0 + (size_t)r) * ld + k0 + c);
        int byte = (((r << 6) + c) << 1) ^ ((r & 7) << 4);
        *(uint4*)((char*)s + byte) = v;
    }
}

DEV void mma64(const u16* As, const u16* Bs, f32x4 acc[4][4], int wr, int wc, int lane) {
    int rb = (wr << 6) + (lane & 15);
    int cb = (wc << 6) + (lane & 15);
    int ko = (lane >> 4) << 3;                     // k-offset within 32: 0,8,16,24
    #pragma unroll
    for (int kh = 0; kh < 2; ++kh) {
        bf16x8 a[4], b[4];
        #pragma unroll
        for (int i = 0; i < 4; ++i) {
            int ar = rb + (i << 4);
            int ab = (((ar << 6) + (kh << 5) + ko) << 1) ^ ((ar & 7) << 4);
            a[i] = *(const bf16x8*)((const char*)As + ab);
            int br = cb + (i << 4);
            int bb = (((br << 6) + (kh << 5) + ko) << 1) ^ ((br & 7) << 4);
            b[i] = *(const bf16x8*)((const char*)Bs + bb);
        }
        #pragma unroll
        for (int i = 0; i < 4; ++i)
            #pragma unroll
            for (int j = 0; j < 4; ++j)
                acc[i][j] = __builtin_amdgcn_mfma_f32_16x16x32_bf16(a[i], b[j], acc[i][j], 0, 0, 0);
    }
}

#define MG_PROLOG(NT)                                        \
    int tid = threadIdx.x, lane = tid & 63, w = tid >> 6;    \
    int wr = w >> 1, wc = w & 1;                             \
    int bm = blockIdx.x / (NT), bn = blockIdx.x % (NT);      \
    size_t m0 = (size_t)bm << 7; int n0 = bn << 7;           \
    f32x4 acc[4][4];                                         \
    { f32x4 zz = {0.f, 0.f, 0.f, 0.f};                       \
      _Pragma("unroll") for (int i = 0; i < 4; ++i)          \
      _Pragma("unroll") for (int j = 0; j < 4; ++j) acc[i][j] = zz; }

// P = x @ BpreT^T : M=40000 KP=128 N=768 -> Pr|Pz|Ph bf16. Grid 313*6.
__global__ __launch_bounds__(256) void k_mg_p(
    const u16* __restrict__ A, const u16* __restrict__ BT,
    u16* __restrict__ Pr, u16* __restrict__ Pz, u16* __restrict__ Ph) {
    __shared__ u16 As[8192], Bs[8192];
    MG_PROLOG(6)
    for (int k0 = 0; k0 < 128; k0 += 64) {
        __syncthreads();
        stage128x64(A, m0, 128, k0, As, tid);
        stage128x64(BT, (size_t)n0, 128, k0, Bs, tid);
        __syncthreads();
        mma64(As, Bs, acc, wr, wc, lane);
    }
    int arr = bn >> 1;
    u16* dst = arr == 0 ? Pr : (arr == 1 ? Pz : Ph);
    int nn0 = ((bn & 1) << 7) + (wc << 6) + (lane & 15);
    int row0 = (int)m0 + (wr << 6) + ((lane >> 4) << 2);
    #pragma unroll
    for (int mi = 0; mi < 4; ++mi)
        #pragma unroll
        for (int r = 0; r < 4; ++r) {
            int m = row0 + mi * 16 + r;
            if (m >= 40000) continue;
            #pragma unroll
            for (int ni = 0; ni < 4; ++ni)
                dst[(size_t)m * 256 + nn0 + ni * 16] = f2b(acc[mi][ni][r]);
        }
}

// Pn = fnode_b @ BonT^T -> d_out f32. M=20000 KP=128 N=256. Grid 157*2.
__global__ __launch_bounds__(256) void k_mg_pn(
    const u16* __restrict__ A, const u16* __restrict__ BT, float* __restrict__ Pn) {
    __shared__ u16 As[8192], Bs[8192];
    MG_PROLOG(2)
    for (int k0 = 0; k0 < 128; k0 += 64) {
        __syncthreads();
        stage128x64(A, m0, 128, k0, As, tid);
        stage128x64(BT, (size_t)n0, 128, k0, Bs, tid);
        __syncthreads();
        mma64(As, Bs, acc, wr, wc, lane);
    }
    int nn0 = n0 + (wc << 6) + (lane & 15);
    int row0 = (int)m0 + (wr << 6) + ((lane >> 4) << 2);
    #pragma unroll
    for (int mi = 0; mi < 4; ++mi)
        #pragma unroll
        for (int r = 0; r < 4; ++r) {
            int m = row0 + mi * 16 + r;
            if (m >= 20000) continue;
            #pragma unroll
            for (int ni = 0; ni < 4; ++ni)
                Pn[(size_t)m * 256 + nn0 + ni * 16] = acc[mi][ni][r];
        }
}

// Uh = h @ BuT^T : M=40000 KP=256 N=256 bf16. Grid 313*2.
__global__ __launch_bounds__(256) void k_mg_uh(
    const u16* __restrict__ A, const u16* __restrict__ BT, u16* __restrict__ C) {
    __shared__ u16 As[8192], Bs[8192];
    MG_PROLOG(2)
    for (int k0 = 0; k0 < 256; k0 += 64) {
        __syncthreads();
        stage128x64(A, m0, 256, k0, As, tid);
        stage128x64(BT, (size_t)n0, 256, k0, Bs, tid);
        __syncthreads();
        mma64(As, Bs, acc, wr, wc, lane);
    }
    int nn0 = n0 + (wc << 6) + (lane & 15);
    int row0 = (int)m0 + (wr << 6) + ((lane >> 4) << 2);
    #pragma unroll
    for (int mi = 0; mi < 4; ++mi)
        #pragma unroll
        for (int r = 0; r < 4; ++r) {
            int m = row0 + mi * 16 + r;
            if (m >= 40000) continue;
            #pragma unroll
            for (int ni = 0; ni < 4; ++ni)
                C[(size_t)m * 256 + nn0 + ni * 16] = f2b(acc[mi][ni][r]);
        }
}

// Fused dual GEMM + GRU update. M=40000 KP=256 N=256. Grid 313*2. LDS 64KB.
__global__ __launch_bounds__(256) void k_mg_fused(
    const u16* __restrict__ sumh, const u16* __restrict__ sumgh,
    const u16* __restrict__ BzT, const u16* __restrict__ BhT,
    const u16* __restrict__ Pz, const u16* __restrict__ Ph,
    const float* __restrict__ bz, const float* __restrict__ bh,
    u16* __restrict__ h) {
    __shared__ u16 As1[8192], As2[8192], Bs1[8192], Bs2[8192];
    int tid = threadIdx.x, lane = tid & 63, w = tid >> 6;
    int wr = w >> 1, wc = w & 1;
    int bm = blockIdx.x >> 1, bn = blockIdx.x & 1;
    size_t m0 = (size_t)bm << 7; int n0 = bn << 7;
    f32x4 aZ[4][4], aH[4][4];
    { f32x4 zz = {0.f, 0.f, 0.f, 0.f};
      #pragma unroll
      for (int i = 0; i < 4; ++i)
          #pragma unroll
          for (int j = 0; j < 4; ++j) { aZ[i][j] = zz; aH[i][j] = zz; } }
    for (int k0 = 0; k0 < 256; k0 += 64) {
        __syncthreads();
        stage128x64(sumh,  m0, 256, k0, As1, tid);
        stage128x64(sumgh, m0, 256, k0, As2, tid);
        stage128x64(BzT, (size_t)n0, 256, k0, Bs1, tid);
        stage128x64(BhT, (size_t)n0, 256, k0, Bs2, tid);
        __syncthreads();
        mma64(As1, Bs1, aZ, wr, wc, lane);
        mma64(As2, Bs2, aH, wr, wc, lane);
    }
    int nn0 = n0 + (wc << 6) + (lane & 15);
    int row0 = (int)m0 + (wr << 6) + ((lane >> 4) << 2);
    float bzv[4], bhv[4];
    #pragma unroll
    for (int ni = 0; ni < 4; ++ni) { bzv[ni] = bz[nn0 + ni * 16]; bhv[ni] = bh[nn0 + ni * 16]; }
    #pragma unroll
    for (int mi = 0; mi < 4; ++mi)
        #pragma unroll
        for (int r = 0; r < 4; ++r) {
            int m = row0 + mi * 16 + r;
            if (m >= 40000) continue;
            #pragma unroll
            for (int ni = 0; ni < 4; ++ni) {
                size_t o = (size_t)m * 256 + nn0 + ni * 16;
                float z   = sigm(aZ[mi][ni][r] + b2f(Pz[o]) + bzv[ni]);
                float pre = tanh_(aH[mi][ni][r] + b2f(Ph[o]) + bhv[ni]);
                float ov  = (1.0f - z) * b2f(sumh[o]) + z * pre;
                if (m == 0) ov = 0.0f;
                h[o] = f2b(ov);
            }
        }
}

// out = gelu(nei_b @ BohT^T + Pn + bo), in-place on d_out. M=20000 KP=256 N=256.
__global__ __launch_bounds__(256) void k_mg_out(
    const u16* __restrict__ A, const u16* __restrict__ BT,
    const float* __restrict__ bo, float* __restrict__ out) {
    __shared__ u16 As[8192], Bs[8192];
    MG_PROLOG(2)
    for (int k0 = 0; k0 < 256; k0 += 64) {
        __syncthreads();
        stage128x64(A, m0, 256, k0, As, tid);
        stage128x64(BT, (size_t)n0, 256, k0, Bs, tid);
        __syncthreads();
        mma64(As, Bs, acc, wr, wc, lane);
    }
    int nn0 = n0 + (wc << 6) + (lane & 15);
    int row0 = (int)m0 + (wr << 6) + ((lane >> 4) << 2);
    float bov[4];
    #pragma unroll
    for (int ni = 0; ni < 4; ++ni) bov[ni] = bo[nn0 + ni * 16];
    #pragma unroll
    for (int mi = 0; mi < 4; ++mi)
        #pragma unroll
        for (int r = 0; r < 4; ++r) {
            int m = row0 + mi * 16 + r;
            if (m >= 20000) continue;
            #pragma unroll
            for (int ni = 0; ni < 4; ++ni) {
                size_t o = (size_t)m * 256 + nn0 + ni * 16;
                float v = gelu_(acc[mi][ni][r] + out[o] + bov[ni]);
                out[o] = (m == 0) ? 0.0f : v;
            }
        }
}

// ---------------------------------------------------------------------------
// Depth 1 (h==0): h = sigm(Pz+bz)*tanh(Ph+bh). Grid 5000x256 (8 bf16/thread).
__global__ __launch_bounds__(256) void k_depth1(
    const u16* __restrict__ Pz, const u16* __restrict__ Ph,
    const float* __restrict__ bz, const float* __restrict__ bh,
    u16* __restrict__ h) {
    int idx = blockIdx.x * 256 + threadIdx.x;
    int e = idx >> 5, c = (idx & 31) << 3;
    size_t o = (size_t)e * 256 + c;
    float pz[8], ph[8], r[8];
    u4tof8(*(const uint4*)(Pz + o), pz);
    u4tof8(*(const uint4*)(Ph + o), ph);
    #pragma unroll
    for (int q = 0; q < 8; ++q)
        r[q] = (e == 0) ? 0.0f : sigm(pz[q] + bz[c + q]) * tanh_(ph[q] + bh[c + q]);
    *(uint4*)(h + o) = f8tou4(r);
}

// sumh/sumgh gather. Grid 5000x256 (8 edges/block, 8 bf16/thread).
__global__ __launch_bounds__(256) void k_gather_edge(
    const u16* __restrict__ h, const u16* __restrict__ Uh,
    const u16* __restrict__ Pr, const float* __restrict__ urb,
    const int* __restrict__ bgraph,
    u16* __restrict__ sumh, u16* __restrict__ sumgh) {
    int e = (blockIdx.x << 3) + (threadIdx.x >> 5);
    int c = (threadIdx.x & 31) << 3;
    size_t o = (size_t)e * 256 + c;
    float pr[8];
    u4tof8(*(const uint4*)(Pr + o), pr);
    #pragma unroll
    for (int q = 0; q < 8; ++q) pr[q] += urb[c + q];
    float sh[8] = {}, sg[8] = {};
    #pragma unroll
    for (int j = 0; j < 6; ++j) {
        int b = bgraph[e * 6 + j];
        float hv[8], uv[8];
        u4tof8(*(const uint4*)(h  + (size_t)b * 256 + c), hv);
        u4tof8(*(const uint4*)(Uh + (size_t)b * 256 + c), uv);
        #pragma unroll
        for (int q = 0; q < 8; ++q) {
            sh[q] += hv[q];
            sg[q] += sigm(pr[q] + uv[q]) * hv[q];
        }
    }
    *(uint4*)(sumh  + o) = f8tou4(sh);
    *(uint4*)(sumgh + o) = f8tou4(sg);
}

// nei_b[n] = bf16(sum_j h[agraph[n][j]]). Grid 2500x256.
__global__ __launch_bounds__(256) void k_gather_node(
    const u16* __restrict__ h, const int* __restrict__ agraph,
    u16* __restrict__ nei) {
    int n = (blockIdx.x << 3) + (threadIdx.x >> 5);
    int c = (threadIdx.x & 31) << 3;
    float s[8] = {};
    #pragma unroll
    for (int j = 0; j < 6; ++j) {
        int a = agraph[n * 6 + j];
        float hv[8];
        u4tof8(*(const uint4*)(h + (size_t)a * 256 + c), hv);
        #pragma unroll
        for (int q = 0; q < 8; ++q) s[q] += hv[q];
    }
    *(uint4*)(nei + (size_t)n * 256 + c) = f8tou4(s);
}

// ---------------------------------------------------------------------------
extern "C" void kernel_launch(void* const* d_in, const int* in_sizes, int n_in,
                              void* d_out, int out_size, void* d_ws, size_t ws_size,
                              hipStream_t stream) {
    if (ws_size < WS_BYTES) return;

    const float* fnode  = (const float*)d_in[0];
    const float* fmess  = (const float*)d_in[1];
    const int*   agraph = (const int*)d_in[2];
    const int*   bgraph = (const int*)d_in[3];
    const float* Wz  = (const float*)d_in[4];
    const float* bz  = (const float*)d_in[5];
    const float* Wr  = (const float*)d_in[6];
    const float* Ur  = (const float*)d_in[7];
    const float* urb = (const float*)d_in[8];
    const float* Wh  = (const float*)d_in[9];
    const float* bh  = (const float*)d_in[10];
    const float* Wo  = (const float*)d_in[11];
    const float* bo  = (const float*)d_in[12];

    char* base = (char*)d_ws;
    u16* h     = (u16*)(base + OB_H);
    u16* sumh  = (u16*)(base + OB_SH);
    u16* x     = (u16*)(base + OB_SH);    // overlay (dead before sumh written)
    u16* sumgh = (u16*)(base + OB_SGH);
    u16* fb    = (u16*)(base + OB_SGH);   // overlay
    u16* Uh    = (u16*)(base + OB_UH);
    u16* neib  = (u16*)(base + OB_UH);    // overlay (after loop)
    u16* BpreT = (u16*)(base + OB_BPRE);  // overlay (dead before Uh written)
    u16* BzT   = (u16*)(base + OB_BZ);
    u16* BhT   = (u16*)(base + OB_BH);
    u16* BuT   = (u16*)(base + OB_BU);
    u16* BohT  = (u16*)(base + OB_BOH);
    u16* BonT  = (u16*)(base + OB_BON);
    u16* Pr    = (u16*)(base + OB_PR);
    u16* Pz    = (u16*)(base + OB_PZ);
    u16* Ph    = (u16*)(base + OB_PH);
    float* out = (float*)d_out;

    hipLaunchKernelGGL(k_repack, dim3(384), dim3(256), 0, stream,
                       Wz, Wr, Ur, Wh, Wo, BpreT, BzT, BhT, BuT, BohT, BonT);
    hipLaunchKernelGGL(k_build_x, dim3(40000), dim3(128), 0, stream, fnode, fmess, x);
    hipLaunchKernelGGL(k_build_fb, dim3(10000), dim3(256), 0, stream, fnode, fb);
    hipLaunchKernelGGL(k_mg_p,  dim3(313 * 6), dim3(256), 0, stream, x, BpreT, Pr, Pz, Ph);
    hipLaunchKernelGGL(k_mg_pn, dim3(157 * 2), dim3(256), 0, stream, fb, BonT, out);
    hipLaunchKernelGGL(k_depth1, dim3(5000), dim3(256), 0, stream, Pz, Ph, bz, bh, h);
    for (int d = 1; d < 4; ++d) {
        hipLaunchKernelGGL(k_mg_uh, dim3(313 * 2), dim3(256), 0, stream, h, BuT, Uh);
        hipLaunchKernelGGL(k_gather_edge, dim3(5000), dim3(256), 0, stream,
                           h, Uh, Pr, urb, bgraph, sumh, sumgh);
        hipLaunchKernelGGL(k_mg_fused, dim3(313 * 2), dim3(256), 0, stream,
                           sumh, sumgh, BzT, BhT, Pz, Ph, bz, bh, h);
    }
    hipLaunchKernelGGL(k_gather_node, dim3(2500), dim3(256), 0, stream, h, agraph, neib);
    hipLaunchKernelGGL(k_mg_out, dim3(157 * 2), dim3(256), 0, stream, neib, BohT, bo, out);
}